// Round 3
// baseline (749.220 us; speedup 1.0000x reference)
//
#include <hip/hip_runtime.h>

#define BB 4
#define NN 10000
#define EE 160000
#define HID 256
#define NHEAD 8

// ---- prep: What[k][h] = sum_d W_edge[k][h*32+d] * att_edge[h][d]  (64x8)
__global__ void k_prep(const float* __restrict__ We, const float* __restrict__ ae,
                       float* __restrict__ What) {
  int t = threadIdx.x;  // 512 threads
  int k = t >> 3, hh = t & 7;
  float s = 0.f;
#pragma unroll
  for (int d = 0; d < 32; ++d) s += We[k * HID + hh * 32 + d] * ae[hh * 32 + d];
  What[k * NHEAD + hh] = s;
}

// ---- projection: waves 0-3: h = nf@W_node (+ssrc/sdst); waves 4-7: res = nf@W_res
__global__ __launch_bounds__(512, 2) void k_proj(
    const float* __restrict__ nf, const float* __restrict__ Wn,
    const float* __restrict__ Wr, const float* __restrict__ as_,
    const float* __restrict__ ad_, float* __restrict__ h,
    float* __restrict__ res, float* __restrict__ ssrc, float* __restrict__ sdst) {
  const int t = threadIdx.x;
  const int c = t & 255;
  const bool isH = t < 256;
  const float* __restrict__ W = isH ? Wn : Wr;
  float4 w[32];
#pragma unroll
  for (int k4 = 0; k4 < 32; ++k4) {
    w[k4].x = W[(4 * k4 + 0) * HID + c];
    w[k4].y = W[(4 * k4 + 1) * HID + c];
    w[k4].z = W[(4 * k4 + 2) * HID + c];
    w[k4].w = W[(4 * k4 + 3) * HID + c];
  }
  const float va = isH ? as_[c] : 0.f, vd = isH ? ad_[c] : 0.f;
  for (int bn = blockIdx.x; bn < BB * NN; bn += gridDim.x) {
    const float4* __restrict__ row = reinterpret_cast<const float4*>(nf + (size_t)bn * 128);
    float acc = 0.f;
#pragma unroll
    for (int k4 = 0; k4 < 32; ++k4) {
      float4 a = row[k4];  // block-uniform address -> scalar loads
      acc += a.x * w[k4].x + a.y * w[k4].y + a.z * w[k4].z + a.w * w[k4].w;
    }
    if (isH) {
      h[(size_t)bn * HID + c] = acc;
      float ps = acc * va, pd = acc * vd;
#pragma unroll
      for (int off = 16; off; off >>= 1) {
        ps += __shfl_xor(ps, off, 32);
        pd += __shfl_xor(pd, off, 32);
      }
      if ((c & 31) == 0) {
        ssrc[bn * NHEAD + (c >> 5)] = ps;
        sdst[bn * NHEAD + (c >> 5)] = pd;
      }
    } else {
      res[(size_t)bn * HID + c] = acc;
    }
  }
}

// ---- edge logits (no atomics; max computed in k_agg via CSR)
__global__ __launch_bounds__(256) void k_elogit(
    const float* __restrict__ ea, const int* __restrict__ ei,
    const float* __restrict__ What, const float* __restrict__ ssrc,
    const float* __restrict__ sdst, float* __restrict__ logits) {
  __shared__ float sea[32 * 65];
  __shared__ float sw[64 * NHEAD];
  const int t = threadIdx.x;
  sw[t] = What[t];
  sw[t + 256] = What[t + 256];
  const int g0 = blockIdx.x * 32;
  const float* base = ea + (size_t)g0 * 64;
#pragma unroll
  for (int j = 0; j < 8; ++j) {
    int f = t + j * 256;
    sea[(f >> 6) * 65 + (f & 63)] = base[f];
  }
  __syncthreads();
  const int il = t >> 3, hh = t & 7;
  const int g = g0 + il;
  float acc = 0.f;
#pragma unroll
  for (int k = 0; k < 64; ++k) acc += sea[il * 65 + k] * sw[k * NHEAD + hh];
  const int b = g / EE, e = g - b * EE;
  const int src = ei[e], dst = ei[EE + e];
  float lg = ssrc[((size_t)b * NN + src) * NHEAD + hh] +
             sdst[((size_t)b * NN + dst) * NHEAD + hh] + acc;
  lg = lg > 0.f ? lg : 0.2f * lg;
  logits[(size_t)g * NHEAD + hh] = lg;
}

// ---- CSR build: histogram, scan, scatter
__global__ void k_hist(const int* __restrict__ ei, int* __restrict__ cnt) {
  int e = blockIdx.x * 256 + threadIdx.x;
  if (e < EE) atomicAdd(&cnt[ei[EE + e]], 1);
}

__global__ __launch_bounds__(1024) void k_scan(const int* __restrict__ cnt,
                                               int* __restrict__ off) {
  __shared__ int ls[1024];
  const int t = threadIdx.x;
  int own = 0;
  int deg[10];
  if (t < 1000) {
#pragma unroll
    for (int i = 0; i < 10; ++i) { deg[i] = cnt[t * 10 + i]; own += deg[i]; }
  }
  ls[t] = own;
  __syncthreads();
  for (int s = 1; s < 1024; s <<= 1) {
    int v = 0;
    if (t >= s) v = ls[t - s];
    __syncthreads();
    if (t >= s) ls[t] += v;
    __syncthreads();
  }
  if (t < 1000) {
    int start = ls[t] - own;
#pragma unroll
    for (int i = 0; i < 10; ++i) { off[t * 10 + i] = start; start += deg[i]; }
  }
  if (t == 0) off[NN] = EE;
}

__global__ void k_scatter(const int* __restrict__ ei, const int* __restrict__ off,
                          int* __restrict__ cur, int* __restrict__ perm,
                          int* __restrict__ esrc) {
  int e = blockIdx.x * 256 + threadIdx.x;
  if (e >= EE) return;
  int d = ei[EE + e];
  int pos = off[d] + atomicAdd(&cur[d], 1);
  perm[pos] = e;
  esrc[pos] = ei[e];
}

// ---- aggregation: wave = (batch=wid, node=blockIdx). No atomics.
// In-place: u holds res on entry; on exit u = agg*(1/ssum) + res.
__global__ __launch_bounds__(256) void k_agg(
    const float* __restrict__ ea, const float* __restrict__ h,
    const float* __restrict__ logits, const int* __restrict__ off,
    const int* __restrict__ perm, const int* __restrict__ esrc,
    const float* __restrict__ We, float* __restrict__ u) {
  __shared__ float zsh[4][8 * 65];
  const int wid = threadIdx.x >> 6, l = threadIdx.x & 63;
  const int b = wid, node = blockIdx.x;
  const int start = off[node], end = off[node + 1];
  const int hq = l >> 3;   // head owning this lane's 4 u-channels
  const int hr = l & 7;    // head this lane tracks for logits/ex
  // pass A: per-head max
  float m = -3.0e38f;
  for (int i = start + (l >> 3); i < end; i += 8) {
    int e = perm[i];
    m = fmaxf(m, logits[((size_t)b * EE + e) * 8 + hr]);
  }
  m = fmaxf(m, __shfl_xor(m, 8));
  m = fmaxf(m, __shfl_xor(m, 16));
  m = fmaxf(m, __shfl_xor(m, 32));
  // pass B: accumulate
  float4 u4 = {0.f, 0.f, 0.f, 0.f};
  float z0 = 0.f, z1 = 0.f, z2 = 0.f, z3 = 0.f;
  float z4 = 0.f, z5 = 0.f, z6 = 0.f, z7 = 0.f;
  float ss = 0.f;
  for (int i = start; i < end; ++i) {
    const int e = perm[i];
    const int src = esrc[i];
    const float lg = logits[((size_t)b * EE + e) * 8 + hr];
    const float exl = __expf(lg - m);
    ss += exl;
    const float eal = ea[((size_t)b * EE + e) * 64 + l];
    const float e0 = __shfl(exl, 0), e1 = __shfl(exl, 1);
    const float e2 = __shfl(exl, 2), e3 = __shfl(exl, 3);
    const float e4 = __shfl(exl, 4), e5 = __shfl(exl, 5);
    const float e6 = __shfl(exl, 6), e7 = __shfl(exl, 7);
    z0 += e0 * eal; z1 += e1 * eal; z2 += e2 * eal; z3 += e3 * eal;
    z4 += e4 * eal; z5 += e5 * eal; z6 += e6 * eal; z7 += e7 * eal;
    const float exu = __shfl(exl, hq);
    const float4 hs =
        *reinterpret_cast<const float4*>(h + (((size_t)b * NN + src) << 8) + 4 * l);
    u4.x += exu * hs.x; u4.y += exu * hs.y;
    u4.z += exu * hs.z; u4.w += exu * hs.w;
  }
  // z epilogue: u4 += z[hq] @ We[:, 4l..4l+3]
  zsh[wid][0 * 65 + l] = z0; zsh[wid][1 * 65 + l] = z1;
  zsh[wid][2 * 65 + l] = z2; zsh[wid][3 * 65 + l] = z3;
  zsh[wid][4 * 65 + l] = z4; zsh[wid][5 * 65 + l] = z5;
  zsh[wid][6 * 65 + l] = z6; zsh[wid][7 * 65 + l] = z7;
  const float4* We4 = reinterpret_cast<const float4*>(We);  // [64][64]
  float4* up = reinterpret_cast<float4*>(u + (((size_t)b * NN + node) << 8) + 4 * l);
  const float4 r4 = *up;  // residual (pre-stored by k_proj)
#pragma unroll 8
  for (int k = 0; k < 64; ++k) {
    const float zk = zsh[wid][hq * 65 + k];
    const float4 wv = We4[k * 64 + l];
    u4.x += zk * wv.x; u4.y += zk * wv.y;
    u4.z += zk * wv.z; u4.w += zk * wv.w;
  }
  const float ssq = __shfl(ss, hq);  // lane hq tracks head hq
  const float sc = ssq > 0.f ? 1.f / ssq : 0.f;
  u4.x = u4.x * sc + r4.x; u4.y = u4.y * sc + r4.y;
  u4.z = u4.z * sc + r4.z; u4.w = u4.w * sc + r4.w;
  *up = u4;
}

// ---- final: LayerNorm + ELU over x (= u)
__global__ __launch_bounds__(256) void k_final(
    const float* __restrict__ x_in, const float* __restrict__ gam,
    const float* __restrict__ bet, float* __restrict__ out) {
  const int c = threadIdx.x;
  const float gg = gam[c], bb = bet[c];
  __shared__ float rs1[4], rs2[4];
  const int wid = c >> 6, lane = c & 63;
  for (int bn = blockIdx.x; bn < BB * NN; bn += gridDim.x) {
    const float x = x_in[(size_t)bn * HID + c];
    float s1 = x, s2 = x * x;
#pragma unroll
    for (int off = 32; off; off >>= 1) {
      s1 += __shfl_xor(s1, off, 64);
      s2 += __shfl_xor(s2, off, 64);
    }
    if (lane == 0) { rs1[wid] = s1; rs2[wid] = s2; }
    __syncthreads();
    const float t1 = rs1[0] + rs1[1] + rs1[2] + rs1[3];
    const float t2 = rs2[0] + rs2[1] + rs2[2] + rs2[3];
    __syncthreads();
    const float mu = t1 * (1.f / HID);
    const float var = t2 * (1.f / HID) - mu * mu;
    float y = (x - mu) * rsqrtf(var + 1e-5f) * gg + bb;
    out[(size_t)bn * HID + c] = y > 0.f ? y : expm1f(y);
  }
}

extern "C" void kernel_launch(void* const* d_in, const int* in_sizes, int n_in,
                              void* d_out, int out_size, void* d_ws, size_t ws_size,
                              hipStream_t stream) {
  const float* nf   = (const float*)d_in[0];
  const int*   ei   = (const int*)d_in[1];
  const float* eatt = (const float*)d_in[2];
  const float* Wn   = (const float*)d_in[3];
  const float* We   = (const float*)d_in[4];
  const float* Wr   = (const float*)d_in[5];
  const float* as_  = (const float*)d_in[6];
  const float* ad_  = (const float*)d_in[7];
  const float* ae_  = (const float*)d_in[8];
  const float* gam  = (const float*)d_in[9];
  const float* bet  = (const float*)d_in[10];
  float* out = (float*)d_out;

  char* ws = (char*)d_ws;
  size_t off_b = 0;
  float* h      = (float*)(ws + off_b); off_b += (size_t)BB * NN * HID * 4;
  float* ssrc   = (float*)(ws + off_b); size_t csr_off = off_b; off_b += (size_t)BB * NN * NHEAD * 4;
  float* sdst   = (float*)(ws + off_b); off_b += (size_t)BB * NN * NHEAD * 4;
  float* What   = (float*)(ws + off_b); off_b += 64 * NHEAD * 4;
  float* logits = (float*)(ws + off_b); off_b += (size_t)BB * EE * NHEAD * 4;
  float* u      = (float*)(ws + off_b); off_b += (size_t)BB * NN * HID * 4;
  // CSR arrays alias ssrc/sdst (2.56 MB >= 1.44 MB) — used only AFTER k_elogit.
  char* csr = ws + csr_off;
  int* cnt  = (int*)(csr);
  int* offn = (int*)(csr + 40 * 1024);            // NN+1 ints
  int* cur  = (int*)(csr + 2 * 40 * 1024);
  int* perm = (int*)(csr + 3 * 40 * 1024);        // EE ints
  int* esrc = (int*)(csr + 3 * 40 * 1024 + (size_t)EE * 4);

  hipLaunchKernelGGL(k_prep, dim3(1), dim3(512), 0, stream, We, ae_, What);
  hipLaunchKernelGGL(k_proj, dim3(1536), dim3(512), 0, stream,
                     nf, Wn, Wr, as_, ad_, h, u, ssrc, sdst);
  hipLaunchKernelGGL(k_elogit, dim3(BB * EE / 32), dim3(256), 0, stream,
                     eatt, ei, What, ssrc, sdst, logits);
  hipMemsetAsync(csr, 0, 3 * 40 * 1024, stream);  // cnt, offn, cur
  hipLaunchKernelGGL(k_hist, dim3((EE + 255) / 256), dim3(256), 0, stream, ei, cnt);
  hipLaunchKernelGGL(k_scan, dim3(1), dim3(1024), 0, stream, cnt, offn);
  hipLaunchKernelGGL(k_scatter, dim3((EE + 255) / 256), dim3(256), 0, stream,
                     ei, offn, cur, perm, esrc);
  hipLaunchKernelGGL(k_agg, dim3(NN), dim3(256), 0, stream,
                     eatt, h, logits, offn, perm, esrc, We, u);
  hipLaunchKernelGGL(k_final, dim3(4096), dim3(256), 0, stream,
                     u, gam, bet, out);
}

// Round 4
// 700.759 us; speedup vs baseline: 1.0692x; 1.0692x over previous
//
#include <hip/hip_runtime.h>

#define BB 4
#define NN 10000
#define EE 160000
#define HID 256
#define NHEAD 8
#define RPG 8  // rows per group in k_proj

// ---- prep: What[k][h] = sum_d W_edge[k][h*32+d] * att_edge[h][d]  (64x8)
__global__ void k_prep(const float* __restrict__ We, const float* __restrict__ ae,
                       float* __restrict__ What) {
  int t = threadIdx.x;  // 512 threads
  int k = t >> 3, hh = t & 7;
  float s = 0.f;
#pragma unroll
  for (int d = 0; d < 32; ++d) s += We[k * HID + hh * 32 + d] * ae[hh * 32 + d];
  What[k * NHEAD + hh] = s;
}

// ---- projection: waves 0-3: h = nf@W_node (+ssrc/sdst); waves 4-7: res = nf@W_res
// 8 rows per block: weight-column reload amortized 8x (this was 10.5 GB of L2
// traffic at 1 row/iter -> 483us; compiler remats weights regardless of hints).
__global__ __launch_bounds__(512) void k_proj(
    const float* __restrict__ nf, const float* __restrict__ Wn,
    const float* __restrict__ Wr, const float* __restrict__ as_,
    const float* __restrict__ ad_, float* __restrict__ h,
    float* __restrict__ res, float* __restrict__ ssrc, float* __restrict__ sdst) {
  const int t = threadIdx.x;
  const int c = t & 255;
  const bool isH = t < 256;
  const float* __restrict__ W = isH ? Wn : Wr;
  const size_t bn0 = (size_t)blockIdx.x * RPG;
  const float4* __restrict__ rb = reinterpret_cast<const float4*>(nf) + bn0 * 32;
  float acc[RPG];
#pragma unroll
  for (int r = 0; r < RPG; ++r) acc[r] = 0.f;
#pragma unroll 8
  for (int k4 = 0; k4 < 32; ++k4) {
    float4 wv;
    wv.x = W[(4 * k4 + 0) * HID + c];
    wv.y = W[(4 * k4 + 1) * HID + c];
    wv.z = W[(4 * k4 + 2) * HID + c];
    wv.w = W[(4 * k4 + 3) * HID + c];
#pragma unroll
    for (int r = 0; r < RPG; ++r) {
      const float4 a = rb[r * 32 + k4];  // block-uniform -> scalar load
      acc[r] += a.x * wv.x + a.y * wv.y + a.z * wv.z + a.w * wv.w;
    }
  }
  const float va = isH ? as_[c] : 0.f, vd = isH ? ad_[c] : 0.f;
#pragma unroll
  for (int r = 0; r < RPG; ++r) {
    const size_t bn = bn0 + r;
    if (isH) {
      h[bn * HID + c] = acc[r];
      float ps = acc[r] * va, pd = acc[r] * vd;
#pragma unroll
      for (int off = 16; off; off >>= 1) {
        ps += __shfl_xor(ps, off, 32);
        pd += __shfl_xor(pd, off, 32);
      }
      if ((c & 31) == 0) {
        ssrc[bn * NHEAD + (c >> 5)] = ps;
        sdst[bn * NHEAD + (c >> 5)] = pd;
      }
    } else {
      res[bn * HID + c] = acc[r];
    }
  }
}

// ---- edge logits (no atomics; max computed in k_agg via CSR)
__global__ __launch_bounds__(256) void k_elogit(
    const float* __restrict__ ea, const int* __restrict__ ei,
    const float* __restrict__ What, const float* __restrict__ ssrc,
    const float* __restrict__ sdst, float* __restrict__ logits) {
  __shared__ float sea[32 * 65];
  __shared__ float sw[64 * NHEAD];
  const int t = threadIdx.x;
  sw[t] = What[t];
  sw[t + 256] = What[t + 256];
  const int g0 = blockIdx.x * 32;
  const float* base = ea + (size_t)g0 * 64;
#pragma unroll
  for (int j = 0; j < 8; ++j) {
    int f = t + j * 256;
    sea[(f >> 6) * 65 + (f & 63)] = base[f];
  }
  __syncthreads();
  const int il = t >> 3, hh = t & 7;
  const int g = g0 + il;
  float acc = 0.f;
#pragma unroll
  for (int k = 0; k < 64; ++k) acc += sea[il * 65 + k] * sw[k * NHEAD + hh];
  const int b = g / EE, e = g - b * EE;
  const int src = ei[e], dst = ei[EE + e];
  float lg = ssrc[((size_t)b * NN + src) * NHEAD + hh] +
             sdst[((size_t)b * NN + dst) * NHEAD + hh] + acc;
  lg = lg > 0.f ? lg : 0.2f * lg;
  logits[(size_t)g * NHEAD + hh] = lg;
}

// ---- CSR build: histogram, scan, scatter
__global__ void k_hist(const int* __restrict__ ei, int* __restrict__ cnt) {
  int e = blockIdx.x * 256 + threadIdx.x;
  if (e < EE) atomicAdd(&cnt[ei[EE + e]], 1);
}

__global__ __launch_bounds__(1024) void k_scan(const int* __restrict__ cnt,
                                               int* __restrict__ off) {
  __shared__ int ls[1024];
  const int t = threadIdx.x;
  int own = 0;
  int deg[10];
  if (t < 1000) {
#pragma unroll
    for (int i = 0; i < 10; ++i) { deg[i] = cnt[t * 10 + i]; own += deg[i]; }
  }
  ls[t] = own;
  __syncthreads();
  for (int s = 1; s < 1024; s <<= 1) {
    int v = 0;
    if (t >= s) v = ls[t - s];
    __syncthreads();
    if (t >= s) ls[t] += v;
    __syncthreads();
  }
  if (t < 1000) {
    int start = ls[t] - own;
#pragma unroll
    for (int i = 0; i < 10; ++i) { off[t * 10 + i] = start; start += deg[i]; }
  }
  if (t == 0) off[NN] = EE;
}

__global__ void k_scatter(const int* __restrict__ ei, const int* __restrict__ off,
                          int* __restrict__ cur, int* __restrict__ perm,
                          int* __restrict__ esrc) {
  int e = blockIdx.x * 256 + threadIdx.x;
  if (e >= EE) return;
  int d = ei[EE + e];
  int pos = off[d] + atomicAdd(&cur[d], 1);
  perm[pos] = e;
  esrc[pos] = ei[e];
}

// ---- aggregation: wave = (batch=wid, node=blockIdx). No atomics.
// In-place: u holds res on entry; on exit u = agg*(1/ssum) + res.
__global__ __launch_bounds__(256) void k_agg(
    const float* __restrict__ ea, const float* __restrict__ h,
    const float* __restrict__ logits, const int* __restrict__ off,
    const int* __restrict__ perm, const int* __restrict__ esrc,
    const float* __restrict__ We, float* __restrict__ u) {
  __shared__ float zsh[4][8 * 65];
  const int wid = threadIdx.x >> 6, l = threadIdx.x & 63;
  const int b = wid, node = blockIdx.x;
  const int start = off[node], end = off[node + 1];
  const int hq = l >> 3;   // head owning this lane's 4 u-channels
  const int hr = l & 7;    // head this lane tracks for logits/ex
  // pass A: per-head max
  float m = -3.0e38f;
  for (int i = start + (l >> 3); i < end; i += 8) {
    int e = perm[i];
    m = fmaxf(m, logits[((size_t)b * EE + e) * 8 + hr]);
  }
  m = fmaxf(m, __shfl_xor(m, 8));
  m = fmaxf(m, __shfl_xor(m, 16));
  m = fmaxf(m, __shfl_xor(m, 32));
  // pass B: accumulate
  float4 u4 = {0.f, 0.f, 0.f, 0.f};
  float z0 = 0.f, z1 = 0.f, z2 = 0.f, z3 = 0.f;
  float z4 = 0.f, z5 = 0.f, z6 = 0.f, z7 = 0.f;
  float ss = 0.f;
  for (int i = start; i < end; ++i) {
    const int e = perm[i];
    const int src = esrc[i];
    const float lg = logits[((size_t)b * EE + e) * 8 + hr];
    const float exl = __expf(lg - m);
    ss += exl;
    const float eal = ea[((size_t)b * EE + e) * 64 + l];
    const float e0 = __shfl(exl, 0), e1 = __shfl(exl, 1);
    const float e2 = __shfl(exl, 2), e3 = __shfl(exl, 3);
    const float e4 = __shfl(exl, 4), e5 = __shfl(exl, 5);
    const float e6 = __shfl(exl, 6), e7 = __shfl(exl, 7);
    z0 += e0 * eal; z1 += e1 * eal; z2 += e2 * eal; z3 += e3 * eal;
    z4 += e4 * eal; z5 += e5 * eal; z6 += e6 * eal; z7 += e7 * eal;
    const float exu = __shfl(exl, hq);
    const float4 hs =
        *reinterpret_cast<const float4*>(h + (((size_t)b * NN + src) << 8) + 4 * l);
    u4.x += exu * hs.x; u4.y += exu * hs.y;
    u4.z += exu * hs.z; u4.w += exu * hs.w;
  }
  // z epilogue: u4 += z[hq] @ We[:, 4l..4l+3]
  zsh[wid][0 * 65 + l] = z0; zsh[wid][1 * 65 + l] = z1;
  zsh[wid][2 * 65 + l] = z2; zsh[wid][3 * 65 + l] = z3;
  zsh[wid][4 * 65 + l] = z4; zsh[wid][5 * 65 + l] = z5;
  zsh[wid][6 * 65 + l] = z6; zsh[wid][7 * 65 + l] = z7;
  const float4* We4 = reinterpret_cast<const float4*>(We);  // [64][64]
  float4* up = reinterpret_cast<float4*>(u + (((size_t)b * NN + node) << 8) + 4 * l);
  const float4 r4 = *up;  // residual (pre-stored by k_proj)
#pragma unroll 8
  for (int k = 0; k < 64; ++k) {
    const float zk = zsh[wid][hq * 65 + k];
    const float4 wv = We4[k * 64 + l];
    u4.x += zk * wv.x; u4.y += zk * wv.y;
    u4.z += zk * wv.z; u4.w += zk * wv.w;
  }
  const float ssq = __shfl(ss, hq);  // lane hq tracks head hq
  const float sc = ssq > 0.f ? 1.f / ssq : 0.f;
  u4.x = u4.x * sc + r4.x; u4.y = u4.y * sc + r4.y;
  u4.z = u4.z * sc + r4.z; u4.w = u4.w * sc + r4.w;
  *up = u4;
}

// ---- final: LayerNorm + ELU over x (= u)
__global__ __launch_bounds__(256) void k_final(
    const float* __restrict__ x_in, const float* __restrict__ gam,
    const float* __restrict__ bet, float* __restrict__ out) {
  const int c = threadIdx.x;
  const float gg = gam[c], bb = bet[c];
  __shared__ float rs1[4], rs2[4];
  const int wid = c >> 6, lane = c & 63;
  for (int bn = blockIdx.x; bn < BB * NN; bn += gridDim.x) {
    const float x = x_in[(size_t)bn * HID + c];
    float s1 = x, s2 = x * x;
#pragma unroll
    for (int off = 32; off; off >>= 1) {
      s1 += __shfl_xor(s1, off, 64);
      s2 += __shfl_xor(s2, off, 64);
    }
    if (lane == 0) { rs1[wid] = s1; rs2[wid] = s2; }
    __syncthreads();
    const float t1 = rs1[0] + rs1[1] + rs1[2] + rs1[3];
    const float t2 = rs2[0] + rs2[1] + rs2[2] + rs2[3];
    __syncthreads();
    const float mu = t1 * (1.f / HID);
    const float var = t2 * (1.f / HID) - mu * mu;
    float y = (x - mu) * rsqrtf(var + 1e-5f) * gg + bb;
    out[(size_t)bn * HID + c] = y > 0.f ? y : expm1f(y);
  }
}

extern "C" void kernel_launch(void* const* d_in, const int* in_sizes, int n_in,
                              void* d_out, int out_size, void* d_ws, size_t ws_size,
                              hipStream_t stream) {
  const float* nf   = (const float*)d_in[0];
  const int*   ei   = (const int*)d_in[1];
  const float* eatt = (const float*)d_in[2];
  const float* Wn   = (const float*)d_in[3];
  const float* We   = (const float*)d_in[4];
  const float* Wr   = (const float*)d_in[5];
  const float* as_  = (const float*)d_in[6];
  const float* ad_  = (const float*)d_in[7];
  const float* ae_  = (const float*)d_in[8];
  const float* gam  = (const float*)d_in[9];
  const float* bet  = (const float*)d_in[10];
  float* out = (float*)d_out;

  char* ws = (char*)d_ws;
  size_t off_b = 0;
  float* h      = (float*)(ws + off_b); off_b += (size_t)BB * NN * HID * 4;
  float* ssrc   = (float*)(ws + off_b); size_t csr_off = off_b; off_b += (size_t)BB * NN * NHEAD * 4;
  float* sdst   = (float*)(ws + off_b); off_b += (size_t)BB * NN * NHEAD * 4;
  float* What   = (float*)(ws + off_b); off_b += 64 * NHEAD * 4;
  float* logits = (float*)(ws + off_b); off_b += (size_t)BB * EE * NHEAD * 4;
  float* u      = (float*)(ws + off_b); off_b += (size_t)BB * NN * HID * 4;
  // CSR arrays alias ssrc/sdst (2.56 MB >= 1.44 MB) — used only AFTER k_elogit.
  char* csr = ws + csr_off;
  int* cnt  = (int*)(csr);
  int* offn = (int*)(csr + 40 * 1024);            // NN+1 ints
  int* cur  = (int*)(csr + 2 * 40 * 1024);
  int* perm = (int*)(csr + 3 * 40 * 1024);        // EE ints
  int* esrc = (int*)(csr + 3 * 40 * 1024 + (size_t)EE * 4);

  hipLaunchKernelGGL(k_prep, dim3(1), dim3(512), 0, stream, We, ae_, What);
  hipLaunchKernelGGL(k_proj, dim3(BB * NN / RPG), dim3(512), 0, stream,
                     nf, Wn, Wr, as_, ad_, h, u, ssrc, sdst);
  hipLaunchKernelGGL(k_elogit, dim3(BB * EE / 32), dim3(256), 0, stream,
                     eatt, ei, What, ssrc, sdst, logits);
  hipMemsetAsync(csr, 0, 3 * 40 * 1024, stream);  // cnt, offn, cur
  hipLaunchKernelGGL(k_hist, dim3((EE + 255) / 256), dim3(256), 0, stream, ei, cnt);
  hipLaunchKernelGGL(k_scan, dim3(1), dim3(1024), 0, stream, cnt, offn);
  hipLaunchKernelGGL(k_scatter, dim3((EE + 255) / 256), dim3(256), 0, stream,
                     ei, offn, cur, perm, esrc);
  hipLaunchKernelGGL(k_agg, dim3(NN), dim3(256), 0, stream,
                     eatt, h, logits, offn, perm, esrc, We, u);
  hipLaunchKernelGGL(k_final, dim3(4096), dim3(256), 0, stream,
                     u, gam, bet, out);
}

// Round 5
// 302.232 us; speedup vs baseline: 2.4790x; 2.3186x over previous
//
#include <hip/hip_runtime.h>

#define BB 4
#define NN 10000
#define EE 160000
#define HID 256
#define NHEAD 8

typedef __attribute__((ext_vector_type(8))) short short8v;
typedef __attribute__((ext_vector_type(4))) float f32x4;

__device__ __forceinline__ unsigned short f2bf(float f) {
  unsigned u = __float_as_uint(f);
  unsigned r = (u + 0x7fffu + ((u >> 16) & 1u)) >> 16;
  return (unsigned short)r;
}

// ---- prep: What[k][h] = sum_d W_edge[k][h*32+d] * att_edge[h][d]  (64x8)
__global__ void k_prep(const float* __restrict__ We, const float* __restrict__ ae,
                       float* __restrict__ What) {
  int t = threadIdx.x;  // 512 threads
  int k = t >> 3, hh = t & 7;
  float s = 0.f;
#pragma unroll
  for (int d = 0; d < 32; ++d) s += We[k * HID + hh * 32 + d] * ae[hh * 32 + d];
  What[k * NHEAD + hh] = s;
}

// ---- nf -> bf16 (8 elems/thread)
__global__ __launch_bounds__(256) void k_cvt(const float* __restrict__ nf,
                                             unsigned short* __restrict__ nf16) {
  const int g = blockIdx.x * 256 + threadIdx.x;  // 0..639999
  const float4* s = reinterpret_cast<const float4*>(nf) + (size_t)g * 2;
  const float4 a = s[0], b = s[1];
  short8v v;
  v[0] = f2bf(a.x); v[1] = f2bf(a.y); v[2] = f2bf(a.z); v[3] = f2bf(a.w);
  v[4] = f2bf(b.x); v[5] = f2bf(b.y); v[6] = f2bf(b.z); v[7] = f2bf(b.w);
  *reinterpret_cast<short8v*>(nf16 + (size_t)g * 8) = v;
}

// ---- pack [Wn|Wr] (K=128 x N=512) into mfma B-fragment order:
// Bpack[((gnt*4+ks)*64 + lane)*8 + e] = W[k = ks*32+(lane>>4)*8+e][col = gnt*16+(lane&15)]
__global__ __launch_bounds__(256) void k_pack(const float* __restrict__ Wn,
                                              const float* __restrict__ Wr,
                                              unsigned short* __restrict__ Bpack) {
  const int nt = blockIdx.x;           // 0..31
  const int ks = threadIdx.x >> 6;     // 0..3
  const int l = threadIdx.x & 63;
  const int col = nt * 16 + (l & 15);
  const int k0 = ks * 32 + (l >> 4) * 8;
  const float* __restrict__ src = (nt < 16) ? Wn : Wr;
  const int c2 = col & 255;
  short8v v;
#pragma unroll
  for (int e = 0; e < 8; ++e) v[e] = f2bf(src[(k0 + e) * HID + c2]);
  *reinterpret_cast<short8v*>(Bpack + ((size_t)(nt * 4 + ks) * 64 + l) * 8) = v;
}

// ---- MFMA projection: [h|res] = nf16 @ [Wn|Wr]. 8 waves/block, 64 rows/block.
// wave w: rows base+(w&3)*16; (w>>2)==0 -> h cols 0-255, ==1 -> res cols 0-255.
__global__ __launch_bounds__(512) void k_projm(
    const unsigned short* __restrict__ nf16,
    const unsigned short* __restrict__ Bpack,
    float* __restrict__ h, float* __restrict__ res) {
  const int t = threadIdx.x;
  const int w = t >> 6, l = t & 63;
  const int base = blockIdx.x * 64 + (w & 3) * 16;
  const int nhalf = w >> 2;
  short8v a[4];
#pragma unroll
  for (int ks = 0; ks < 4; ++ks)
    a[ks] = *reinterpret_cast<const short8v*>(
        nf16 + (size_t)(base + (l & 15)) * 128 + ks * 32 + (l >> 4) * 8);
  f32x4 acc[16];
#pragma unroll
  for (int i = 0; i < 16; ++i) acc[i] = (f32x4){0.f, 0.f, 0.f, 0.f};
  const short8v* bp =
      reinterpret_cast<const short8v*>(Bpack) + (size_t)nhalf * 4096 + l;
#pragma unroll
  for (int nt = 0; nt < 16; ++nt) {
#pragma unroll
    for (int ks = 0; ks < 4; ++ks) {
      const short8v bf = bp[(nt * 4 + ks) * 64];
      acc[nt] = __builtin_amdgcn_mfma_f32_16x16x32_bf16(a[ks], bf, acc[nt], 0, 0, 0);
    }
  }
  float* __restrict__ outp = nhalf ? res : h;
#pragma unroll
  for (int nt = 0; nt < 16; ++nt) {
    const int col = nt * 16 + (l & 15);
#pragma unroll
    for (int b = 0; b < 4; ++b) {
      const int row = base + (l >> 4) * 4 + b;
      outp[(size_t)row * HID + col] = acc[nt][b];
    }
  }
}

// ---- per-node attention scalars from h
__global__ __launch_bounds__(256) void k_att(
    const float* __restrict__ h, const float* __restrict__ as_,
    const float* __restrict__ ad_, float* __restrict__ ssrc,
    float* __restrict__ sdst) {
  const int w = threadIdx.x >> 6, l = threadIdx.x & 63;
  const size_t bn = (size_t)blockIdx.x * 4 + w;
  const float4 hv = reinterpret_cast<const float4*>(h + bn * HID)[l];
  const float4 av = reinterpret_cast<const float4*>(as_)[l];
  const float4 dv = reinterpret_cast<const float4*>(ad_)[l];
  float ps = hv.x * av.x + hv.y * av.y + hv.z * av.z + hv.w * av.w;
  float pd = hv.x * dv.x + hv.y * dv.y + hv.z * dv.z + hv.w * dv.w;
#pragma unroll
  for (int off = 1; off <= 4; off <<= 1) {
    ps += __shfl_xor(ps, off);
    pd += __shfl_xor(pd, off);
  }
  if ((l & 7) == 0) {
    ssrc[bn * NHEAD + (l >> 3)] = ps;
    sdst[bn * NHEAD + (l >> 3)] = pd;
  }
}

// ---- edge logits
__global__ __launch_bounds__(256) void k_elogit(
    const float* __restrict__ ea, const int* __restrict__ ei,
    const float* __restrict__ What, const float* __restrict__ ssrc,
    const float* __restrict__ sdst, float* __restrict__ logits) {
  __shared__ float sea[32 * 65];
  __shared__ float sw[64 * NHEAD];
  const int t = threadIdx.x;
  sw[t] = What[t];
  sw[t + 256] = What[t + 256];
  const int g0 = blockIdx.x * 32;
  const float* base = ea + (size_t)g0 * 64;
#pragma unroll
  for (int j = 0; j < 8; ++j) {
    int f = t + j * 256;
    sea[(f >> 6) * 65 + (f & 63)] = base[f];
  }
  __syncthreads();
  const int il = t >> 3, hh = t & 7;
  const int g = g0 + il;
  float acc = 0.f;
#pragma unroll
  for (int k = 0; k < 64; ++k) acc += sea[il * 65 + k] * sw[k * NHEAD + hh];
  const int b = g / EE, e = g - b * EE;
  const int src = ei[e], dst = ei[EE + e];
  float lg = ssrc[((size_t)b * NN + src) * NHEAD + hh] +
             sdst[((size_t)b * NN + dst) * NHEAD + hh] + acc;
  lg = lg > 0.f ? lg : 0.2f * lg;
  logits[(size_t)g * NHEAD + hh] = lg;
}

// ---- CSR build: histogram, scan, scatter
__global__ void k_hist(const int* __restrict__ ei, int* __restrict__ cnt) {
  int e = blockIdx.x * 256 + threadIdx.x;
  if (e < EE) atomicAdd(&cnt[ei[EE + e]], 1);
}

__global__ __launch_bounds__(1024) void k_scan(const int* __restrict__ cnt,
                                               int* __restrict__ off) {
  __shared__ int ls[1024];
  const int t = threadIdx.x;
  int own = 0;
  int deg[10];
  if (t < 1000) {
#pragma unroll
    for (int i = 0; i < 10; ++i) { deg[i] = cnt[t * 10 + i]; own += deg[i]; }
  }
  ls[t] = own;
  __syncthreads();
  for (int s = 1; s < 1024; s <<= 1) {
    int v = 0;
    if (t >= s) v = ls[t - s];
    __syncthreads();
    if (t >= s) ls[t] += v;
    __syncthreads();
  }
  if (t < 1000) {
    int start = ls[t] - own;
#pragma unroll
    for (int i = 0; i < 10; ++i) { off[t * 10 + i] = start; start += deg[i]; }
  }
  if (t == 0) off[NN] = EE;
}

__global__ void k_scatter(const int* __restrict__ ei, const int* __restrict__ off,
                          int* __restrict__ cur, int* __restrict__ perm,
                          int* __restrict__ esrc) {
  int e = blockIdx.x * 256 + threadIdx.x;
  if (e >= EE) return;
  int d = ei[EE + e];
  int pos = off[d] + atomicAdd(&cur[d], 1);
  perm[pos] = e;
  esrc[pos] = ei[e];
}

// ---- aggregation + LN + ELU fused. wave = (batch=wid, node=blockIdx).
// res holds nf@W_res (from k_projm); out = ELU(LN(agg/ssum + res)).
__global__ __launch_bounds__(256) void k_agg(
    const float* __restrict__ ea, const float* __restrict__ h,
    const float* __restrict__ logits, const int* __restrict__ off,
    const int* __restrict__ perm, const int* __restrict__ esrc,
    const float* __restrict__ We, const float* __restrict__ res,
    const float* __restrict__ gam, const float* __restrict__ bet,
    float* __restrict__ out) {
  __shared__ float zsh[4][8 * 65];
  const int wid = threadIdx.x >> 6, l = threadIdx.x & 63;
  const int b = wid, node = blockIdx.x;
  const int start = off[node], end = off[node + 1];
  const int hq = l >> 3;   // head owning this lane's 4 u-channels
  const int hr = l & 7;    // head this lane tracks for logits/ex
  // pass A: per-head max
  float m = -3.0e38f;
  for (int i = start + (l >> 3); i < end; i += 8) {
    int e = perm[i];
    m = fmaxf(m, logits[((size_t)b * EE + e) * 8 + hr]);
  }
  m = fmaxf(m, __shfl_xor(m, 8));
  m = fmaxf(m, __shfl_xor(m, 16));
  m = fmaxf(m, __shfl_xor(m, 32));
  // pass B: accumulate
  float4 u4 = {0.f, 0.f, 0.f, 0.f};
  float z0 = 0.f, z1 = 0.f, z2 = 0.f, z3 = 0.f;
  float z4 = 0.f, z5 = 0.f, z6 = 0.f, z7 = 0.f;
  float ss = 0.f;
  for (int i = start; i < end; ++i) {
    const int e = perm[i];
    const int src = esrc[i];
    const float lg = logits[((size_t)b * EE + e) * 8 + hr];
    const float exl = __expf(lg - m);
    ss += exl;
    const float eal = ea[((size_t)b * EE + e) * 64 + l];
    const float e0 = __shfl(exl, 0), e1 = __shfl(exl, 1);
    const float e2 = __shfl(exl, 2), e3 = __shfl(exl, 3);
    const float e4 = __shfl(exl, 4), e5 = __shfl(exl, 5);
    const float e6 = __shfl(exl, 6), e7 = __shfl(exl, 7);
    z0 += e0 * eal; z1 += e1 * eal; z2 += e2 * eal; z3 += e3 * eal;
    z4 += e4 * eal; z5 += e5 * eal; z6 += e6 * eal; z7 += e7 * eal;
    const float exu = __shfl(exl, hq);
    const float4 hs =
        *reinterpret_cast<const float4*>(h + (((size_t)b * NN + src) << 8) + 4 * l);
    u4.x += exu * hs.x; u4.y += exu * hs.y;
    u4.z += exu * hs.z; u4.w += exu * hs.w;
  }
  // z epilogue: u4 += z[hq] @ We[:, 4l..4l+3]
  zsh[wid][0 * 65 + l] = z0; zsh[wid][1 * 65 + l] = z1;
  zsh[wid][2 * 65 + l] = z2; zsh[wid][3 * 65 + l] = z3;
  zsh[wid][4 * 65 + l] = z4; zsh[wid][5 * 65 + l] = z5;
  zsh[wid][6 * 65 + l] = z6; zsh[wid][7 * 65 + l] = z7;
  const float4* We4 = reinterpret_cast<const float4*>(We);  // [64][64]
  const float4 r4 =
      *reinterpret_cast<const float4*>(res + (((size_t)b * NN + node) << 8) + 4 * l);
#pragma unroll 8
  for (int k = 0; k < 64; ++k) {
    const float zk = zsh[wid][hq * 65 + k];
    const float4 wv = We4[k * 64 + l];
    u4.x += zk * wv.x; u4.y += zk * wv.y;
    u4.z += zk * wv.z; u4.w += zk * wv.w;
  }
  const float ssq = __shfl(ss, hq);  // lane hq tracks head hq
  const float sc = ssq > 0.f ? 1.f / ssq : 0.f;
  u4.x = u4.x * sc + r4.x; u4.y = u4.y * sc + r4.y;
  u4.z = u4.z * sc + r4.z; u4.w = u4.w * sc + r4.w;
  // fused LayerNorm + ELU (wave holds the full 256-channel row)
  float s1 = u4.x + u4.y + u4.z + u4.w;
  float s2 = u4.x * u4.x + u4.y * u4.y + u4.z * u4.z + u4.w * u4.w;
#pragma unroll
  for (int off2 = 1; off2 <= 32; off2 <<= 1) {
    s1 += __shfl_xor(s1, off2);
    s2 += __shfl_xor(s2, off2);
  }
  const float mu = s1 * (1.f / HID);
  const float var = s2 * (1.f / HID) - mu * mu;
  const float rstd = rsqrtf(var + 1e-5f);
  const float4 g4 = reinterpret_cast<const float4*>(gam)[l];
  const float4 b4 = reinterpret_cast<const float4*>(bet)[l];
  float4 y;
  y.x = (u4.x - mu) * rstd * g4.x + b4.x;
  y.y = (u4.y - mu) * rstd * g4.y + b4.y;
  y.z = (u4.z - mu) * rstd * g4.z + b4.z;
  y.w = (u4.w - mu) * rstd * g4.w + b4.w;
  y.x = y.x > 0.f ? y.x : expm1f(y.x);
  y.y = y.y > 0.f ? y.y : expm1f(y.y);
  y.z = y.z > 0.f ? y.z : expm1f(y.z);
  y.w = y.w > 0.f ? y.w : expm1f(y.w);
  *reinterpret_cast<float4*>(out + (((size_t)b * NN + node) << 8) + 4 * l) = y;
}

extern "C" void kernel_launch(void* const* d_in, const int* in_sizes, int n_in,
                              void* d_out, int out_size, void* d_ws, size_t ws_size,
                              hipStream_t stream) {
  const float* nf   = (const float*)d_in[0];
  const int*   ei   = (const int*)d_in[1];
  const float* eatt = (const float*)d_in[2];
  const float* Wn   = (const float*)d_in[3];
  const float* We   = (const float*)d_in[4];
  const float* Wr   = (const float*)d_in[5];
  const float* as_  = (const float*)d_in[6];
  const float* ad_  = (const float*)d_in[7];
  const float* ae_  = (const float*)d_in[8];
  const float* gam  = (const float*)d_in[9];
  const float* bet  = (const float*)d_in[10];
  float* out = (float*)d_out;

  char* ws = (char*)d_ws;
  size_t off_b = 0;
  float* h      = (float*)(ws + off_b); off_b += (size_t)BB * NN * HID * 4;
  float* ssrc   = (float*)(ws + off_b); size_t csr_off = off_b; off_b += (size_t)BB * NN * NHEAD * 4;
  float* sdst   = (float*)(ws + off_b); off_b += (size_t)BB * NN * NHEAD * 4;
  float* What   = (float*)(ws + off_b); off_b += 64 * NHEAD * 4;
  size_t logits_off = off_b;
  float* logits = (float*)(ws + off_b); off_b += (size_t)BB * EE * NHEAD * 4;
  float* res    = (float*)(ws + off_b); off_b += (size_t)BB * NN * HID * 4;
  // nf16 (10.24 MB) and Bpack (128 KB) alias the logits buffer (20.48 MB):
  // written by k_cvt/k_pack, read by k_projm, then logits overwrites (k_elogit).
  unsigned short* nf16  = (unsigned short*)(ws + logits_off);
  unsigned short* Bpack = (unsigned short*)(ws + logits_off + ((size_t)12 << 20));
  // CSR arrays alias ssrc/sdst (2.56 MB >= 1.44 MB) — used only AFTER k_elogit.
  char* csr = ws + csr_off;
  int* cnt  = (int*)(csr);
  int* offn = (int*)(csr + 40 * 1024);            // NN+1 ints
  int* cur  = (int*)(csr + 2 * 40 * 1024);
  int* perm = (int*)(csr + 3 * 40 * 1024);        // EE ints
  int* esrc = (int*)(csr + 3 * 40 * 1024 + (size_t)EE * 4);

  hipLaunchKernelGGL(k_prep, dim3(1), dim3(512), 0, stream, We, ae_, What);
  hipLaunchKernelGGL(k_cvt, dim3(2500), dim3(256), 0, stream, nf, nf16);
  hipLaunchKernelGGL(k_pack, dim3(32), dim3(256), 0, stream, Wn, Wr, Bpack);
  hipLaunchKernelGGL(k_projm, dim3(BB * NN / 64), dim3(512), 0, stream,
                     nf16, Bpack, h, res);
  hipLaunchKernelGGL(k_att, dim3(BB * NN / 4), dim3(256), 0, stream,
                     h, as_, ad_, ssrc, sdst);
  hipLaunchKernelGGL(k_elogit, dim3(BB * EE / 32), dim3(256), 0, stream,
                     eatt, ei, What, ssrc, sdst, logits);
  hipMemsetAsync(csr, 0, 3 * 40 * 1024, stream);  // cnt, offn, cur
  hipLaunchKernelGGL(k_hist, dim3((EE + 255) / 256), dim3(256), 0, stream, ei, cnt);
  hipLaunchKernelGGL(k_scan, dim3(1), dim3(1024), 0, stream, cnt, offn);
  hipLaunchKernelGGL(k_scatter, dim3((EE + 255) / 256), dim3(256), 0, stream,
                     ei, offn, cur, perm, esrc);
  hipLaunchKernelGGL(k_agg, dim3(NN), dim3(256), 0, stream,
                     eatt, h, logits, offn, perm, esrc, We, res, gam, bet, out);
}